// Round 5
// baseline (865.991 us; speedup 1.0000x reference)
//
#include <hip/hip_runtime.h>

// VQ-VAE quantizer: x [B=32, C=64, T=4096] f32, emb [K=1024, D=64] f32.
// Outputs flat f32: quant_out [B*C*T], codebook_loss [1], commitment_loss [1],
// idx [B*T] (written as float).
//
// CORRECTNESS-CRITICAL (validated R2/R3/R4, absmax 3.8e-6 = zero argmin flips):
// the checker recomputes the reference with numpy in f32. d = (S+e2[k])-2*dot
// is ~64 so it is quantized at ulp(64)=7.6e-6; top-2 gaps are ~2e-3 typical but
// ~0.4% of rows tie at quantization level -> argmin decided by numpy's exact
// rounding. Replicated bit-for-bit:
//   S, e2[k]: numpy pairwise_sum of fl(v*v), n=64 (8 accs stride-8, then
//             ((r0+r1)+(r2+r3))+((r4+r5)+(r6+r7)); mul/add separately rounded)
//   dot     : per-candidate single-accumulator FMA chain, i ascending (BLAS)
//   d       : fl(fl(S+e2[k]) - 2*dot); 2*dot exact so fma(-2,d,t) == np
//   argmin  : strict <, ascending k; cross-slice merge via packed u64
//             (bits(d)<<10 | k) — d>0 so bit order == value order.
// DO NOT change chain arithmetic/ordering. DO NOT split D within a chain.
//
// Perf history:
//   R2: 1 thr/row, xr[64] "resident": 453us. VGPR=44 -> x rematerialized in-loop.
//   R3: K-split x4 + dynamic xr index: 1017us (xr -> scratch; emb -> VMEM).
//   R4: readfirstlane + asm-pin xr: 369us, VALUBusy 89%, VGPR 44 -> xr shunted
//       to AGPRs (unified file); VALU issue = 3.0x FMA floor (accvgpr reads).
//   R5: NO long-lived x. NR=16 candidate accs; x re-streamed from global in
//       16-dim chunks (block x-slice = 16KB, L1-resident, re-read 16x). Opaque
//       SGPR offset token per chunk blocks LICM/CSE from re-hoisting x (and
//       blocks epilogue loads CSE'ing with the S loads). Live x = 16.

#define KCB 1024
#define DD 64
#define BB 32
#define TT 4096
#define BT (BB * TT)            // 131072 rows
#define NELEM (BB * DD * TT)    // 8388608

#define KSPLIT 4
#define KPER (KCB / KSPLIT)     // 256 candidates per thread
#define NR 16                   // candidate block (accumulators per thread)
#define ROWS_PER_BLOCK 64

#define WS_LOSS 0
#define WS_E2 64

// e2[k] = numpy pairwise sum of fl(e_i*e_i); also zero the loss accumulator.
__global__ void vq_compute_e2(const float* __restrict__ emb, float* __restrict__ ws) {
#pragma clang fp contract(off)
    int k = blockIdx.x * blockDim.x + threadIdx.x;
    if (k == 0) ws[WS_LOSS] = 0.0f;
    if (k < KCB) {
        const float* e = emb + (size_t)k * DD;
        float r[8];
#pragma unroll
        for (int j = 0; j < 8; ++j) r[j] = e[j] * e[j];
#pragma unroll
        for (int i = 8; i < 64; i += 8) {
#pragma unroll
            for (int j = 0; j < 8; ++j) r[j] += e[i + j] * e[i + j];
        }
        ws[WS_E2 + k] = ((r[0] + r[1]) + (r[2] + r[3])) + ((r[4] + r[5]) + (r[6] + r[7]));
    }
}

__launch_bounds__(256, 4)
__global__ void vq_main(const float* __restrict__ x, const float* __restrict__ emb,
                        float* __restrict__ out, float* __restrict__ ws) {
#pragma clang fp contract(off)
    const int tid = threadIdx.x;
    const int lane = tid & 63;                                // row-within-block
    const int ks = __builtin_amdgcn_readfirstlane(tid >> 6);  // k-slice, SGPR

    const int row = blockIdx.x * ROWS_PER_BLOCK + lane;  // 64|4096 => b uniform
    const int b = row >> 12;
    const int t = row & (TT - 1);

    __shared__ unsigned long long redu[ROWS_PER_BLOCK];
    __shared__ float bsum;
    if (tid < ROWS_PER_BLOCK) redu[tid] = ~0ull;
    if (tid == 0) bsum = 0.0f;
    __syncthreads();

    const float* xp = x + (size_t)b * DD * TT + t;  // dim c at xp[c*TT]

    // S = numpy pairwise sum of fl(x_i*x_i), n=64 (loads die into r[] here)
    float r[8];
#pragma unroll
    for (int j = 0; j < 8; ++j) { float v = xp[(size_t)j * TT]; r[j] = v * v; }
#pragma unroll
    for (int i = 8; i < 64; i += 8) {
#pragma unroll
        for (int j = 0; j < 8; ++j) { float v = xp[(size_t)(i + j) * TT]; r[j] += v * v; }
    }
    const float S = ((r[0] + r[1]) + (r[2] + r[3])) + ((r[4] + r[5]) + (r[6] + r[7]));

    const float* e2p = ws + WS_E2;

    float best = 3.4e38f;
    int bidx = 0;

    const int k0 = ks * KPER;
#pragma unroll 1
    for (int kk = 0; kk < KPER; kk += NR) {
        const int kb = k0 + kk;
        const float* ep = emb + (size_t)kb * DD;  // uniform -> s_load broadcast
        float d[NR];
#pragma unroll
        for (int c = 0; c < NR; ++c) d[c] = 0.0f;

#pragma unroll
        for (int ih = 0; ih < DD / 16; ++ih) {
            // Opaque zero SGPR offset: addresses not provably loop-invariant
            // -> LICM/CSE cannot hoist x reloads (keeps live-x at 16; defends
            // against R2/R4's remat/AGPR-shunt pathology).
            int off = 0;
            asm volatile("" : "+s"(off));
            const float* xq = (const float*)((const char*)xp + off);
            float xv[16];
#pragma unroll
            for (int j = 0; j < 16; ++j) xv[j] = xq[(size_t)(16 * ih + j) * TT];
            // Per-candidate chain order: i ascending (ih outer, j inner) —
            // bit-identical to the sequential BLAS dot.
#pragma unroll
            for (int c = 0; c < NR; ++c) {
#pragma unroll
                for (int j = 0; j < 16; ++j)
                    d[c] = __builtin_fmaf(ep[c * DD + 16 * ih + j], xv[j], d[c]);
            }
        }

#pragma unroll
        for (int c = 0; c < NR; ++c) {
            float tt = S + e2p[kb + c];                 // fl(S + e2)
            float s = __builtin_fmaf(-2.0f, d[c], tt);  // fl(tt - 2d), 2d exact
            if (s < best) { best = s; bidx = kb + c; }  // strict <, ascending k
        }
    }

    // Merge 4 slices: packed (bits(d)<<10 | k); d>0 => bit-monotone; low bits
    // give numpy first-index tie-break.
    unsigned long long packed =
        ((unsigned long long)__float_as_uint(best) << 10) | (unsigned int)bidx;
    atomicMin(&redu[lane], packed);
    __syncthreads();

    const int fidx = (int)(redu[lane] & 1023u);

    // Epilogue: 4-way dim split via wave-uniform branches. x re-read through a
    // fresh opaque token so these loads cannot CSE with the S loads above.
    const float* eql = emb + (size_t)fidx * DD;
    float* oq = out + (size_t)b * DD * TT + t;
    int off2 = 0;
    asm volatile("" : "+s"(off2));
    const float* xq2 = (const float*)((const char*)xp + off2);
    float lsum = 0.0f;
#pragma unroll
    for (int c4 = 0; c4 < DD / 4; ++c4) {
        if (ks == (c4 >> 2)) {   // uniform: s_cmp + s_cbranch
            float4 v = *(const float4*)(eql + 4 * c4);
            oq[(size_t)(4 * c4 + 0) * TT] = v.x;
            oq[(size_t)(4 * c4 + 1) * TT] = v.y;
            oq[(size_t)(4 * c4 + 2) * TT] = v.z;
            oq[(size_t)(4 * c4 + 3) * TT] = v.w;
            float a0 = v.x - xq2[(size_t)(4 * c4 + 0) * TT];
            float a1 = v.y - xq2[(size_t)(4 * c4 + 1) * TT];
            float a2 = v.z - xq2[(size_t)(4 * c4 + 2) * TT];
            float a3 = v.w - xq2[(size_t)(4 * c4 + 3) * TT];
            lsum = __builtin_fmaf(a0, a0, lsum);
            lsum = __builtin_fmaf(a1, a1, lsum);
            lsum = __builtin_fmaf(a2, a2, lsum);
            lsum = __builtin_fmaf(a3, a3, lsum);
        }
    }

    if (ks == 0) out[NELEM + 2 + row] = (float)fidx;

    // wave(64) shuffle reduction, LDS-stage, one global atomic per block
#pragma unroll
    for (int off = 32; off > 0; off >>= 1) lsum += __shfl_down(lsum, off);
    if (lane == 0) atomicAdd(&bsum, lsum);
    __syncthreads();
    if (tid == 0) atomicAdd(ws + WS_LOSS, bsum);
}

__global__ void vq_finalize(const float* __restrict__ ws, float* __restrict__ out) {
    if (threadIdx.x == 0 && blockIdx.x == 0) {
        float M = ws[WS_LOSS] / (float)NELEM;
        out[NELEM + 0] = M;           // codebook_loss
        out[NELEM + 1] = 0.25f * M;   // commitment_loss = BETA * same mean
    }
}

extern "C" void kernel_launch(void* const* d_in, const int* in_sizes, int n_in,
                              void* d_out, int out_size, void* d_ws, size_t ws_size,
                              hipStream_t stream) {
    const float* x = (const float*)d_in[0];
    const float* emb = (const float*)d_in[1];
    float* out = (float*)d_out;
    float* ws = (float*)d_ws;

    vq_compute_e2<<<KCB / 256, 256, 0, stream>>>(emb, ws);
    vq_main<<<BT / ROWS_PER_BLOCK, 256, 0, stream>>>(x, emb, out, ws);
    vq_finalize<<<1, 64, 0, stream>>>(ws, out);
}

// Round 6
// 361.469 us; speedup vs baseline: 2.3958x; 2.3958x over previous
//
#include <hip/hip_runtime.h>

// VQ-VAE quantizer: x [B=32, C=64, T=4096] f32, emb [K=1024, D=64] f32.
// Outputs flat f32: quant_out [B*C*T], codebook_loss [1], commitment_loss [1],
// idx [B*T] (written as float).
//
// CORRECTNESS-CRITICAL (validated R2/R4/R5, absmax 3.8e-6 = zero argmin flips):
// the checker recomputes the reference with numpy in f32. d = (S+e2[k])-2*dot
// is ~64 -> quantized at ulp(64)=7.6e-6; a fraction of rows tie at that level
// so argmin is decided by numpy's exact rounding. Replicated bit-for-bit:
//   S, e2[k]: numpy pairwise_sum of fl(v*v), n=64 (8 accs stride-8, then
//             ((r0+r1)+(r2+r3))+((r4+r5)+(r6+r7)); mul/add separately rounded)
//   dot     : per-candidate single-accumulator FMA chain, i ascending (BLAS)
//   d       : fl(fl(S+e2[k]) - 2*dot)  via fma(-2,dot,S+e2) (2*dot exact)
//   argmin  : strict <, ascending k; cross-slice merge via packed u64
//             (bits(d)<<10 | k) — d>0 so bit order == value order.
// DO NOT change chain arithmetic/ordering. DO NOT split D within a chain.
//
// Perf history:
//   R2 453us: x[64] "in regs" -> compiler remat'd global loads in-loop (VGPR 44).
//   R3 1017us: dynamic xr index -> scratch; non-uniform ks -> VMEM emb.
//   R4 369us: asm-pinned xr -> AGPR shunt; VALU = 3x FMA floor (accvgpr traffic).
//   R5 828us: NR=16 + token'd x re-stream -> d[16] SPILLED (WRITE +35MB = 64B/thr).
//   Lesson: allocator refuses >~50 long-lived VGPRs here. So R6 keeps NO bulk
//   per-thread state: x lives in LDS (stride 65 = conflict-free, odd stride
//   also prevents b64 merging), emb stays SGPR-broadcast (uniform ks), live
//   state = 16 accs + 4 staged x ~= 40 VGPR. Token per kk iter stops LDS-read
//   CSE across iterations (R2 pathology).

#define KCB 1024
#define DD 64
#define BB 32
#define TT 4096
#define BT (BB * TT)            // 131072 rows
#define NELEM (BB * DD * TT)    // 8388608

#define KSPLIT 4
#define KPER (KCB / KSPLIT)     // 256 candidates per wave
#define NR 16                   // candidates per k-chunk
#define ROWS_PER_BLOCK 64
#define XSTRIDE 65              // odd -> (r+i)%32 banking, 2 lanes/bank = free

#define WS_LOSS 0
#define WS_E2 64

// e2[k] = numpy pairwise sum of fl(e_i*e_i); also zero the loss accumulator.
__global__ void vq_compute_e2(const float* __restrict__ emb, float* __restrict__ ws) {
#pragma clang fp contract(off)
    int k = blockIdx.x * blockDim.x + threadIdx.x;
    if (k == 0) ws[WS_LOSS] = 0.0f;
    if (k < KCB) {
        const float* e = emb + (size_t)k * DD;
        float r[8];
#pragma unroll
        for (int j = 0; j < 8; ++j) r[j] = e[j] * e[j];
#pragma unroll
        for (int i = 8; i < 64; i += 8) {
#pragma unroll
            for (int j = 0; j < 8; ++j) r[j] += e[i + j] * e[i + j];
        }
        ws[WS_E2 + k] = ((r[0] + r[1]) + (r[2] + r[3])) + ((r[4] + r[5]) + (r[6] + r[7]));
    }
}

__launch_bounds__(256, 4)
__global__ void vq_main(const float* __restrict__ x, const float* __restrict__ emb,
                        float* __restrict__ out, float* __restrict__ ws) {
#pragma clang fp contract(off)
    const int tid = threadIdx.x;
    const int lane = tid & 63;                                // row-within-block
    const int ks = __builtin_amdgcn_readfirstlane(tid >> 6);  // k-slice, SGPR

    const int row0 = blockIdx.x * ROWS_PER_BLOCK;             // 64 | 4096 -> b uniform
    const int b = row0 >> 12;
    const int t0 = row0 & (TT - 1);
    const int row = row0 + lane;

    __shared__ float x_lds[ROWS_PER_BLOCK * XSTRIDE];
    __shared__ unsigned long long redu[ROWS_PER_BLOCK];
    __shared__ float bsum;
    if (tid < ROWS_PER_BLOCK) redu[tid] = ~0ull;
    if (tid == 0) bsum = 0.0f;

    // Stage x-slice: wave ks loads channels c = 4j+ks (uniform per wave),
    // global read coalesced (64 consecutive t), LDS write (r+c)%32 conflict-free.
    const float* xg = x + (size_t)b * DD * TT + t0 + lane;
#pragma unroll
    for (int j = 0; j < DD / KSPLIT; ++j) {
        const int c = 4 * j + ks;
        x_lds[lane * XSTRIDE + c] = xg[(size_t)c * TT];
    }
    __syncthreads();

    // S = numpy pairwise sum of fl(x_i*x_i), n=64 (each wave computes its own
    // copy from LDS; reads are conflict-free).
    const int xbase = lane * XSTRIDE;
    float r[8];
#pragma unroll
    for (int j = 0; j < 8; ++j) { float v = x_lds[xbase + j]; r[j] = v * v; }
#pragma unroll
    for (int i = 8; i < 64; i += 8) {
#pragma unroll
        for (int j = 0; j < 8; ++j) { float v = x_lds[xbase + i + j]; r[j] += v * v; }
    }
    const float S = ((r[0] + r[1]) + (r[2] + r[3])) + ((r[4] + r[5]) + (r[6] + r[7]));

    const float* e2p = ws + WS_E2;

    float best = 3.4e38f;
    int bidx = 0;

    const int k0 = ks * KPER;
#pragma unroll 1
    for (int kk = 0; kk < KPER; kk += NR) {
        const int kb = k0 + kk;
        const float* ep = emb + (size_t)kb * DD;  // uniform -> s_load broadcast

        // Opaque zero index: x_lds read addresses differ symbolically per kk
        // iteration -> no CSE/hoist of 64 x values across the k-loop.
        int xo = 0;
        asm volatile("" : "+v"(xo));

        float d[NR];
#pragma unroll
        for (int c = 0; c < NR; ++c) d[c] = 0.0f;

#pragma unroll
        for (int ih = 0; ih < DD / 4; ++ih) {
            float xv0 = x_lds[xbase + xo + 4 * ih + 0];
            float xv1 = x_lds[xbase + xo + 4 * ih + 1];
            float xv2 = x_lds[xbase + xo + 4 * ih + 2];
            float xv3 = x_lds[xbase + xo + 4 * ih + 3];
            // Per-candidate chain: i ascending (ih outer, j inner) — bit-equal
            // to the sequential BLAS dot.
#pragma unroll
            for (int c = 0; c < NR; ++c) {
                float acc = d[c];
                acc = __builtin_fmaf(ep[c * DD + 4 * ih + 0], xv0, acc);
                acc = __builtin_fmaf(ep[c * DD + 4 * ih + 1], xv1, acc);
                acc = __builtin_fmaf(ep[c * DD + 4 * ih + 2], xv2, acc);
                acc = __builtin_fmaf(ep[c * DD + 4 * ih + 3], xv3, acc);
                d[c] = acc;
            }
        }

#pragma unroll
        for (int c = 0; c < NR; ++c) {
            float tt = S + e2p[kb + c];                 // fl(S + e2)
            float s = __builtin_fmaf(-2.0f, d[c], tt);  // fl(tt - 2*dot)
            if (s < best) { best = s; bidx = kb + c; }  // strict <, ascending k
        }
    }

    // Merge 4 slices: packed (bits(d)<<10 | k); d>0 => bit-monotone; low bits
    // give numpy first-index tie-break.
    unsigned long long packed =
        ((unsigned long long)__float_as_uint(best) << 10) | (unsigned int)bidx;
    atomicMin(&redu[lane], packed);
    __syncthreads();

    const int fidx = (int)(redu[lane] & 1023u);

    // Epilogue: 4-way dim split via wave-uniform branches; x re-read from LDS.
    const float* eql = emb + (size_t)fidx * DD;
    float* oq = out + (size_t)b * DD * TT + t0 + lane;
    float lsum = 0.0f;
#pragma unroll
    for (int c4 = 0; c4 < DD / 4; ++c4) {
        if (ks == (c4 >> 2)) {   // uniform: s_cmp + s_cbranch
            float4 v = *(const float4*)(eql + 4 * c4);
            oq[(size_t)(4 * c4 + 0) * TT] = v.x;
            oq[(size_t)(4 * c4 + 1) * TT] = v.y;
            oq[(size_t)(4 * c4 + 2) * TT] = v.z;
            oq[(size_t)(4 * c4 + 3) * TT] = v.w;
            float a0 = v.x - x_lds[xbase + 4 * c4 + 0];
            float a1 = v.y - x_lds[xbase + 4 * c4 + 1];
            float a2 = v.z - x_lds[xbase + 4 * c4 + 2];
            float a3 = v.w - x_lds[xbase + 4 * c4 + 3];
            lsum = __builtin_fmaf(a0, a0, lsum);
            lsum = __builtin_fmaf(a1, a1, lsum);
            lsum = __builtin_fmaf(a2, a2, lsum);
            lsum = __builtin_fmaf(a3, a3, lsum);
        }
    }

    if (ks == 0) out[NELEM + 2 + row] = (float)fidx;

    // wave(64) shuffle reduction, LDS-stage, one global atomic per block
#pragma unroll
    for (int off = 32; off > 0; off >>= 1) lsum += __shfl_down(lsum, off);
    if (lane == 0) atomicAdd(&bsum, lsum);
    __syncthreads();
    if (tid == 0) atomicAdd(ws + WS_LOSS, bsum);
}

__global__ void vq_finalize(const float* __restrict__ ws, float* __restrict__ out) {
    if (threadIdx.x == 0 && blockIdx.x == 0) {
        float M = ws[WS_LOSS] / (float)NELEM;
        out[NELEM + 0] = M;           // codebook_loss
        out[NELEM + 1] = 0.25f * M;   // commitment_loss = BETA * same mean
    }
}

extern "C" void kernel_launch(void* const* d_in, const int* in_sizes, int n_in,
                              void* d_out, int out_size, void* d_ws, size_t ws_size,
                              hipStream_t stream) {
    const float* x = (const float*)d_in[0];
    const float* emb = (const float*)d_in[1];
    float* out = (float*)d_out;
    float* ws = (float*)d_ws;

    vq_compute_e2<<<KCB / 256, 256, 0, stream>>>(emb, ws);
    vq_main<<<BT / ROWS_PER_BLOCK, 256, 0, stream>>>(x, emb, out, ws);
    vq_finalize<<<1, 64, 0, stream>>>(ws, out);
}